// Round 3
// baseline (2575.240 us; speedup 1.0000x reference)
//
#include <hip/hip_runtime.h>
#include <hip/hip_bf16.h>

#define BB 64
#define TT 512
#define FF 1024
#define KK 64

// ---------------- Emission GEMM (round-1 version, measured ~83us): ----------------
// em[row][k] = dot(X[row,:], W[k,:]) + b[k]; row = b*T+t, 64x64 tile, 256 threads.
#define BM 64
#define BF 64
#define LDA 68  // padded LDS stride: 272 B rows, 16B-aligned, breaks pow-2 bank conflicts

__global__ __launch_bounds__(256)
void emission_kernel(const float* __restrict__ X, const float* __restrict__ W,
                     const float* __restrict__ bias, float* __restrict__ em)
{
    __shared__ float As[BF][LDA];   // As[f][m]  (transposed)
    __shared__ float Bs[BF][LDA];   // Bs[f][k]  (transposed)
    const int tid = threadIdx.x;
    const int row0 = blockIdx.x * BM;
    const int tm = tid & 15;
    const int tn = tid >> 4;
    const int lq = tid & 15;
    const int lr = tid >> 4;

    float acc[4][4];
#pragma unroll
    for (int i = 0; i < 4; ++i)
#pragma unroll
        for (int jj = 0; jj < 4; ++jj) acc[i][jj] = 0.f;

    for (int f0 = 0; f0 < FF; f0 += BF) {
#pragma unroll
        for (int p = 0; p < 4; ++p) {
            const int r = p * 16 + lr;
            float4 a = *(const float4*)(X + (size_t)(row0 + r) * FF + f0 + lq * 4);
            As[lq * 4 + 0][r] = a.x;
            As[lq * 4 + 1][r] = a.y;
            As[lq * 4 + 2][r] = a.z;
            As[lq * 4 + 3][r] = a.w;
            float4 w = *(const float4*)(W + (size_t)r * FF + f0 + lq * 4);
            Bs[lq * 4 + 0][r] = w.x;
            Bs[lq * 4 + 1][r] = w.y;
            Bs[lq * 4 + 2][r] = w.z;
            Bs[lq * 4 + 3][r] = w.w;
        }
        __syncthreads();
#pragma unroll
        for (int f = 0; f < BF; ++f) {
            float4 a = *(const float4*)&As[f][tm * 4];
            float4 b = *(const float4*)&Bs[f][tn * 4];
            acc[0][0] += a.x * b.x; acc[0][1] += a.x * b.y; acc[0][2] += a.x * b.z; acc[0][3] += a.x * b.w;
            acc[1][0] += a.y * b.x; acc[1][1] += a.y * b.y; acc[1][2] += a.y * b.z; acc[1][3] += a.y * b.w;
            acc[2][0] += a.z * b.x; acc[2][1] += a.z * b.y; acc[2][2] += a.z * b.z; acc[2][3] += a.z * b.w;
            acc[3][0] += a.w * b.x; acc[3][1] += a.w * b.y; acc[3][2] += a.w * b.z; acc[3][3] += a.w * b.w;
        }
        __syncthreads();
    }

    const float4 b4 = *(const float4*)(bias + tn * 4);
#pragma unroll
    for (int i = 0; i < 4; ++i) {
        float4 o;
        o.x = acc[i][0] + b4.x;
        o.y = acc[i][1] + b4.y;
        o.z = acc[i][2] + b4.z;
        o.w = acc[i][3] + b4.w;
        *(float4*)(em + (size_t)(row0 + tm * 4 + i) * KK + tn * 4) = o;
    }
}

// ---------------- Viterbi: forward on ONE wave (no barriers in hot loop) ----------------
// lane j = next tag. Per step: 64 readlane broadcasts (independent), 128 adds,
// tournament tree (63 nodes, depth 6, left-wins => first-index argmax), bit-exact
// (s_i + trans[i][j]) + e_j. e/mask double-buffered. Monotone-mask early exit.
// Backtrack: 4 waves, 8 segments x 64-hypothesis replay (round-2 validated).
__global__ __launch_bounds__(256)
void viterbi_kernel(const float* __restrict__ em, const void* __restrict__ maskp,
                    const float* __restrict__ startT, const float* __restrict__ endT,
                    const float* __restrict__ trans, float* __restrict__ pred)
{
    const int b = blockIdx.x;
    const int tid = threadIdx.x;
    const int w = tid >> 6;
    const int j = tid & 63;

    __shared__ unsigned char hist[TT][KK];     // 32 KB
    __shared__ unsigned char hypo[8][64][64];  // 32 KB
    __shared__ int bt_sh;

    // mask layout detection (lengths >= 256 so mask[0][1] is true):
    const unsigned char* m8 = (const unsigned char*)maskp;
    const int* m32 = (const int*)maskp;
    const bool u8m = (m8[1] != 0);

    if (w == 0) {
        float tc[KK];   // trans column j
#pragma unroll
        for (int i = 0; i < KK; ++i) tc[i] = trans[i * KK + j];

        const float* emb = em + (size_t)b * TT * KK;
        float score = startT[j] + emb[j];       // t = 0
        const float endv = endT[j];

        float e_cur = emb[KK + j];              // t = 1 prefetch
        int   m_cur = u8m ? (int)m8[b * TT + 1] : m32[b * TT + 1];

        int t = 1;
        for (; t < TT; ++t) {
            const int tn = (t + 1 < TT) ? (t + 1) : (TT - 1);
            const float e_next = emb[(size_t)tn * KK + j];     // prefetch next
            const int   m_next = u8m ? (int)m8[b * TT + tn] : m32[b * TT + tn];

            if (!m_cur) break;   // mask is a length mask: monotone, done forever

            float cv[4]; int ci[4];
#pragma unroll
            for (int c = 0; c < 4; ++c) {
                float tv[16]; int ti[16];
#pragma unroll
                for (int q = 0; q < 16; ++q) {
                    const int i = c * 16 + q;
                    const float si = __uint_as_float(
                        (unsigned)__builtin_amdgcn_readlane((int)__float_as_uint(score), i));
                    tv[q] = (si + tc[i]) + e_cur;   // reference association order
                    ti[q] = i;
                }
                // contiguous-pair tree; >= keeps LEFT (lower index) => first-index argmax
#pragma unroll
                for (int n = 8; n >= 1; n >>= 1)
#pragma unroll
                    for (int q = 0; q < n; ++q) {
                        const bool cgt = tv[2 * q] >= tv[2 * q + 1];
                        tv[q] = cgt ? tv[2 * q] : tv[2 * q + 1];
                        ti[q] = cgt ? ti[2 * q] : ti[2 * q + 1];
                    }
                cv[c] = tv[0]; ci[c] = ti[0];
            }
            const bool c01 = cv[0] >= cv[1];
            const float v01 = c01 ? cv[0] : cv[1];
            const int   i01 = c01 ? ci[0] : ci[1];
            const bool c23 = cv[2] >= cv[3];
            const float v23 = c23 ? cv[2] : cv[3];
            const int   i23 = c23 ? ci[2] : ci[3];
            const bool cf = v01 >= v23;
            score = cf ? v01 : v23;
            hist[t][j] = (unsigned char)(cf ? i01 : i23);

            e_cur = e_next; m_cur = m_next;
        }
        for (; t < TT; ++t) hist[t][j] = (unsigned char)j;   // identity tail

        score += endv;
        // first-index argmax over 64 lanes (one-time; serial chain is fine)
        float bm = __uint_as_float((unsigned)__builtin_amdgcn_readlane((int)__float_as_uint(score), 0));
        int bt = 0;
#pragma unroll
        for (int i = 1; i < KK; ++i) {
            const float si = __uint_as_float(
                (unsigned)__builtin_amdgcn_readlane((int)__float_as_uint(score), i));
            if (si > bm) { bm = si; bt = i; }
        }
        if (j == 0) bt_sh = bt;
    }

    __syncthreads();   // hist + bt_sh complete; waves 1-3 join here

    // Phase A: all-hypothesis segment replay; wave w -> segments 2w, 2w+1
#pragma unroll
    for (int ss = 0; ss < 2; ++ss) {
        const int s = w * 2 + ss;
        int tag = j;
        if (s == 7) {
            hypo[7][63][j] = (unsigned char)j;            // tag at t=511
            for (int t = TT - 1; t >= 7 * 64 + 1; --t) {
                tag = hist[t][tag];
                hypo[7][t - 1 - 7 * 64][j] = (unsigned char)tag;
            }
        } else {
            for (int t = (s + 1) * 64; t >= s * 64 + 1; --t) {
                tag = hist[t][tag];
                hypo[s][t - 1 - s * 64][j] = (unsigned char)tag;
            }
        }
    }
    __syncthreads();

    // Phase B: compose boundary tags (uniform; broadcast LDS reads)
    const int bt = bt_sh;
    int rows_[8];
    rows_[7] = bt;
#pragma unroll
    for (int s = 6; s >= 0; --s) rows_[s] = hypo[s + 1][0][rows_[s + 1]];

    // Phase C: emit; wave w -> segments 2w, 2w+1; lane j -> time 64s+j
    float* pb = pred + (size_t)b * TT;
#pragma unroll
    for (int ss = 0; ss < 2; ++ss) {
        const int s = w * 2 + ss;
        pb[s * 64 + j] = (float)hypo[s][j][rows_[s]];
    }
}

extern "C" void kernel_launch(void* const* d_in, const int* in_sizes, int n_in,
                              void* d_out, int out_size, void* d_ws, size_t ws_size,
                              hipStream_t stream) {
    const float* X      = (const float*)d_in[0];
    const void*  mask   = d_in[1];
    const float* W      = (const float*)d_in[2];
    const float* bias   = (const float*)d_in[3];
    const float* startT = (const float*)d_in[4];
    const float* endT   = (const float*)d_in[5];
    const float* trans  = (const float*)d_in[6];

    float* em   = (float*)d_out;
    float* pred = (float*)d_out + (size_t)BB * TT * KK;

    emission_kernel<<<(BB * TT) / BM, 256, 0, stream>>>(X, W, bias, em);
    viterbi_kernel<<<BB, 256, 0, stream>>>(em, mask, startT, endT, trans, pred);
}

// Round 4
// 1344.164 us; speedup vs baseline: 1.9159x; 1.9159x over previous
//
#include <hip/hip_runtime.h>
#include <hip/hip_bf16.h>

#define BB 64
#define TT 512
#define FF 1024
#define KK 64

// ---------------- Emission GEMM: em[row][k] = dot(X[row,:], W[k,:]) + b[k] ----------------
// 64x64 tile, 256 threads. Reg-staged double-buffer (T14): issue next tile's
// global loads before compute; latency hides under the 64-f FMA phase.
#define BM 64
#define BF 64
#define LDA 68  // padded LDS stride: 272 B rows, 16B-aligned, breaks pow-2 bank conflicts

__global__ __launch_bounds__(256)
void emission_kernel(const float* __restrict__ X, const float* __restrict__ W,
                     const float* __restrict__ bias, float* __restrict__ em)
{
    __shared__ float As[BF][LDA];   // As[f][m]  (transposed)
    __shared__ float Bs[BF][LDA];   // Bs[f][k]  (transposed)
    const int tid = threadIdx.x;
    const int row0 = blockIdx.x * BM;
    const int tm = tid & 15;
    const int tn = tid >> 4;
    const int lq = tid & 15;
    const int lr = tid >> 4;

    float acc[4][4];
#pragma unroll
    for (int i = 0; i < 4; ++i)
#pragma unroll
        for (int jj = 0; jj < 4; ++jj) acc[i][jj] = 0.f;

    float4 ra[4], rw[4];
    // prologue: load tile f0=0
#pragma unroll
    for (int p = 0; p < 4; ++p) {
        const int r = p * 16 + lr;
        ra[p] = *(const float4*)(X + (size_t)(row0 + r) * FF + lq * 4);
        rw[p] = *(const float4*)(W + (size_t)r * FF + lq * 4);
    }
#pragma unroll
    for (int p = 0; p < 4; ++p) {
        const int r = p * 16 + lr;
        As[lq * 4 + 0][r] = ra[p].x;
        As[lq * 4 + 1][r] = ra[p].y;
        As[lq * 4 + 2][r] = ra[p].z;
        As[lq * 4 + 3][r] = ra[p].w;
        Bs[lq * 4 + 0][r] = rw[p].x;
        Bs[lq * 4 + 1][r] = rw[p].y;
        Bs[lq * 4 + 2][r] = rw[p].z;
        Bs[lq * 4 + 3][r] = rw[p].w;
    }
    __syncthreads();

    for (int f0 = BF; f0 <= FF; f0 += BF) {
        const bool more = (f0 < FF);
        if (more) {   // issue next-tile loads EARLY; land during compute
#pragma unroll
            for (int p = 0; p < 4; ++p) {
                const int r = p * 16 + lr;
                ra[p] = *(const float4*)(X + (size_t)(row0 + r) * FF + f0 + lq * 4);
                rw[p] = *(const float4*)(W + (size_t)r * FF + f0 + lq * 4);
            }
        }
#pragma unroll
        for (int f = 0; f < BF; ++f) {
            float4 a = *(const float4*)&As[f][tm * 4];
            float4 b = *(const float4*)&Bs[f][tn * 4];
            acc[0][0] += a.x * b.x; acc[0][1] += a.x * b.y; acc[0][2] += a.x * b.z; acc[0][3] += a.x * b.w;
            acc[1][0] += a.y * b.x; acc[1][1] += a.y * b.y; acc[1][2] += a.y * b.z; acc[1][3] += a.y * b.w;
            acc[2][0] += a.z * b.x; acc[2][1] += a.z * b.y; acc[2][2] += a.z * b.z; acc[2][3] += a.z * b.w;
            acc[3][0] += a.w * b.x; acc[3][1] += a.w * b.y; acc[3][2] += a.w * b.z; acc[3][3] += a.w * b.w;
        }
        if (more) {
            __syncthreads();   // everyone done READING current tile
#pragma unroll
            for (int p = 0; p < 4; ++p) {
                const int r = p * 16 + lr;
                As[lq * 4 + 0][r] = ra[p].x;
                As[lq * 4 + 1][r] = ra[p].y;
                As[lq * 4 + 2][r] = ra[p].z;
                As[lq * 4 + 3][r] = ra[p].w;
                Bs[lq * 4 + 0][r] = rw[p].x;
                Bs[lq * 4 + 1][r] = rw[p].y;
                Bs[lq * 4 + 2][r] = rw[p].z;
                Bs[lq * 4 + 3][r] = rw[p].w;
            }
            __syncthreads();   // writes visible
        }
    }

    const float4 b4 = *(const float4*)(bias + tn * 4);
#pragma unroll
    for (int i = 0; i < 4; ++i) {
        float4 o;
        o.x = acc[i][0] + b4.x;
        o.y = acc[i][1] + b4.y;
        o.z = acc[i][2] + b4.z;
        o.w = acc[i][3] + b4.w;
        *(float4*)(em + (size_t)(row0 + tm * 4 + i) * KK + tn * 4) = o;
    }
}

// ---------------- Viterbi: forward on ONE wave (no barriers in hot loop) ----------------
// lane j = next tag. Chunk-8 tournament tree (63 nodes, depth 6, left-wins on >=
// => first-index argmax), bit-exact (s_i + trans[i][j]) + e_j. e/mask prefetched.
// launch_bounds(256,1): full VGPR budget -> tc[64] stays in registers (round-3
// regression was tc[] spilling to scratch at the default 88-reg budget).
// Backtrack: 4 waves, 8 segments x 64-hypothesis replay (validated rounds 2-3).
__global__ __launch_bounds__(256, 1)
void viterbi_kernel(const float* __restrict__ em, const void* __restrict__ maskp,
                    const float* __restrict__ startT, const float* __restrict__ endT,
                    const float* __restrict__ trans, float* __restrict__ pred)
{
    const int b = blockIdx.x;
    const int tid = threadIdx.x;
    const int w = tid >> 6;
    const int j = tid & 63;

    __shared__ unsigned char hist[TT][KK];     // 32 KB
    __shared__ unsigned char hypo[8][64][64];  // 32 KB
    __shared__ int bt_sh;

    // mask layout detection (lengths >= 256 so mask[0][1] is true):
    const unsigned char* m8 = (const unsigned char*)maskp;
    const int* m32 = (const int*)maskp;
    const bool u8m = (m8[1] != 0);

    if (w == 0) {
        float tc[KK];   // trans column j — MUST stay in VGPRs
#pragma unroll
        for (int i = 0; i < KK; ++i) tc[i] = trans[i * KK + j];

        const float* emb = em + (size_t)b * TT * KK;
        float score = startT[j] + emb[j];       // t = 0
        const float endv = endT[j];

        float e_cur = emb[KK + j];              // t = 1 prefetch
        int   m_cur = u8m ? (int)m8[b * TT + 1] : m32[b * TT + 1];

        int t = 1;
        for (; t < TT; ++t) {
            const int tn2 = (t + 1 < TT) ? (t + 1) : (TT - 1);
            const float e_next = emb[(size_t)tn2 * KK + j];     // prefetch next
            const int   m_next = u8m ? (int)m8[b * TT + tn2] : m32[b * TT + tn2];

            if (!m_cur) break;   // length mask: monotone, done forever

            float cv[8]; int ci[8];
#pragma unroll
            for (int c = 0; c < 8; ++c) {
                float tv[8]; int ti[8];
#pragma unroll
                for (int q = 0; q < 8; ++q) {
                    const int i = c * 8 + q;
                    const float si = __uint_as_float(
                        (unsigned)__builtin_amdgcn_readlane((int)__float_as_uint(score), i));
                    tv[q] = (si + tc[i]) + e_cur;   // reference association order
                    ti[q] = i;
                }
#pragma unroll
                for (int n = 4; n >= 1; n >>= 1)
#pragma unroll
                    for (int q = 0; q < n; ++q) {
                        const bool cgt = tv[2 * q] >= tv[2 * q + 1];
                        tv[q] = cgt ? tv[2 * q] : tv[2 * q + 1];
                        ti[q] = cgt ? ti[2 * q] : ti[2 * q + 1];
                    }
                cv[c] = tv[0]; ci[c] = ti[0];
            }
#pragma unroll
            for (int n = 4; n >= 1; n >>= 1)
#pragma unroll
                for (int q = 0; q < n; ++q) {
                    const bool cgt = cv[2 * q] >= cv[2 * q + 1];
                    cv[q] = cgt ? cv[2 * q] : cv[2 * q + 1];
                    ci[q] = cgt ? ci[2 * q] : ci[2 * q + 1];
                }
            score = cv[0];
            hist[t][j] = (unsigned char)ci[0];

            e_cur = e_next; m_cur = m_next;
        }
        for (; t < TT; ++t) hist[t][j] = (unsigned char)j;   // identity tail

        score += endv;
        // first-index argmax over 64 lanes (one-time; serial chain is fine)
        float bm = __uint_as_float((unsigned)__builtin_amdgcn_readlane((int)__float_as_uint(score), 0));
        int bt = 0;
#pragma unroll
        for (int i = 1; i < KK; ++i) {
            const float si = __uint_as_float(
                (unsigned)__builtin_amdgcn_readlane((int)__float_as_uint(score), i));
            if (si > bm) { bm = si; bt = i; }
        }
        if (j == 0) bt_sh = bt;
    }

    __syncthreads();   // hist + bt_sh complete; waves 1-3 join here

    // Phase A: all-hypothesis segment replay; wave w -> segments 2w, 2w+1
#pragma unroll
    for (int ss = 0; ss < 2; ++ss) {
        const int s = w * 2 + ss;
        int tag = j;
        if (s == 7) {
            hypo[7][63][j] = (unsigned char)j;            // tag at t=511
            for (int t = TT - 1; t >= 7 * 64 + 1; --t) {
                tag = hist[t][tag];
                hypo[7][t - 1 - 7 * 64][j] = (unsigned char)tag;
            }
        } else {
            for (int t = (s + 1) * 64; t >= s * 64 + 1; --t) {
                tag = hist[t][tag];
                hypo[s][t - 1 - s * 64][j] = (unsigned char)tag;
            }
        }
    }
    __syncthreads();

    // Phase B: compose boundary tags (uniform; broadcast LDS reads)
    const int bt = bt_sh;
    int rows_[8];
    rows_[7] = bt;
#pragma unroll
    for (int s = 6; s >= 0; --s) rows_[s] = hypo[s + 1][0][rows_[s + 1]];

    // Phase C: emit; wave w -> segments 2w, 2w+1; lane j -> time 64s+j
    float* pb = pred + (size_t)b * TT;
#pragma unroll
    for (int ss = 0; ss < 2; ++ss) {
        const int s = w * 2 + ss;
        pb[s * 64 + j] = (float)hypo[s][j][rows_[s]];
    }
}

extern "C" void kernel_launch(void* const* d_in, const int* in_sizes, int n_in,
                              void* d_out, int out_size, void* d_ws, size_t ws_size,
                              hipStream_t stream) {
    const float* X      = (const float*)d_in[0];
    const void*  mask   = d_in[1];
    const float* W      = (const float*)d_in[2];
    const float* bias   = (const float*)d_in[3];
    const float* startT = (const float*)d_in[4];
    const float* endT   = (const float*)d_in[5];
    const float* trans  = (const float*)d_in[6];

    float* em   = (float*)d_out;
    float* pred = (float*)d_out + (size_t)BB * TT * KK;

    emission_kernel<<<(BB * TT) / BM, 256, 0, stream>>>(X, W, bias, em);
    viterbi_kernel<<<BB, 256, 0, stream>>>(em, mask, startT, endT, trans, pred);
}

// Round 5
// 1280.751 us; speedup vs baseline: 2.0107x; 1.0495x over previous
//
#include <hip/hip_runtime.h>
#include <hip/hip_bf16.h>

#define BB 64
#define TT 512
#define FF 1024
#define KK 64

// ---------------- Emission GEMM (round-1 version, measured ~83us twice) ----------------
#define BM 64
#define BF 64
#define LDA 68  // padded LDS stride: 272 B rows, 16B-aligned, breaks pow-2 bank conflicts

__global__ __launch_bounds__(256)
void emission_kernel(const float* __restrict__ X, const float* __restrict__ W,
                     const float* __restrict__ bias, float* __restrict__ em)
{
    __shared__ float As[BF][LDA];   // As[f][m]  (transposed)
    __shared__ float Bs[BF][LDA];   // Bs[f][k]  (transposed)
    const int tid = threadIdx.x;
    const int row0 = blockIdx.x * BM;
    const int tm = tid & 15;
    const int tn = tid >> 4;
    const int lq = tid & 15;
    const int lr = tid >> 4;

    float acc[4][4];
#pragma unroll
    for (int i = 0; i < 4; ++i)
#pragma unroll
        for (int jj = 0; jj < 4; ++jj) acc[i][jj] = 0.f;

    for (int f0 = 0; f0 < FF; f0 += BF) {
#pragma unroll
        for (int p = 0; p < 4; ++p) {
            const int r = p * 16 + lr;
            float4 a = *(const float4*)(X + (size_t)(row0 + r) * FF + f0 + lq * 4);
            As[lq * 4 + 0][r] = a.x;
            As[lq * 4 + 1][r] = a.y;
            As[lq * 4 + 2][r] = a.z;
            As[lq * 4 + 3][r] = a.w;
            float4 w = *(const float4*)(W + (size_t)r * FF + f0 + lq * 4);
            Bs[lq * 4 + 0][r] = w.x;
            Bs[lq * 4 + 1][r] = w.y;
            Bs[lq * 4 + 2][r] = w.z;
            Bs[lq * 4 + 3][r] = w.w;
        }
        __syncthreads();
#pragma unroll
        for (int f = 0; f < BF; ++f) {
            float4 a = *(const float4*)&As[f][tm * 4];
            float4 b = *(const float4*)&Bs[f][tn * 4];
            acc[0][0] += a.x * b.x; acc[0][1] += a.x * b.y; acc[0][2] += a.x * b.z; acc[0][3] += a.x * b.w;
            acc[1][0] += a.y * b.x; acc[1][1] += a.y * b.y; acc[1][2] += a.y * b.z; acc[1][3] += a.y * b.w;
            acc[2][0] += a.z * b.x; acc[2][1] += a.z * b.y; acc[2][2] += a.z * b.z; acc[2][3] += a.z * b.w;
            acc[3][0] += a.w * b.x; acc[3][1] += a.w * b.y; acc[3][2] += a.w * b.z; acc[3][3] += a.w * b.w;
        }
        __syncthreads();
    }

    const float4 b4 = *(const float4*)(bias + tn * 4);
#pragma unroll
    for (int i = 0; i < 4; ++i) {
        float4 o;
        o.x = acc[i][0] + b4.x;
        o.y = acc[i][1] + b4.y;
        o.z = acc[i][2] + b4.z;
        o.w = acc[i][3] + b4.w;
        *(float4*)(em + (size_t)(row0 + tm * 4 + i) * KK + tn * 4) = o;
    }
}

// ---------------- Viterbi ----------------
// Forward: ONE wave, lane j = next tag, no barriers in hot loop. The trans
// column lives in LDS (tbuf), re-read each step as 2x ds_read_b128 per chunk:
//   - physical 4-float block p = b ^ (j&7): 8 lane-groups -> 8 distinct 4-bank
//     windows = b128 bandwidth floor, no pathological conflicts.
//   - double copy indexed by (t&1): load address varies per step => not
//     loop-invariant => compiler CANNOT hoist 64 floats into regs (the
//     register-spill death of rounds 1-4).
// Chunk-8 tournament, left-wins-on->= (first-index argmax), bit-exact
// (s_i + tc_i) + e_j. Backtrack: 4 waves, 8-segment hypothesis replay
// (validated r2-r4); tbuf is reused as hypo.
__global__ __launch_bounds__(256)
void viterbi_kernel(const float* __restrict__ em, const void* __restrict__ maskp,
                    const float* __restrict__ startT, const float* __restrict__ endT,
                    const float* __restrict__ trans, float* __restrict__ pred)
{
    const int b = blockIdx.x;
    const int tid = threadIdx.x;
    const int w = tid >> 6;
    const int j = tid & 63;

    __shared__ unsigned char hist[TT][KK];   // 32 KB
    __shared__ float tbuf[2][KK][KK];        // 32 KB; forward: swizzled trans^T x2; backtrack: hypo
    __shared__ int bt_sh;

    unsigned char (*hypo)[64][64] = (unsigned char (*)[64][64])tbuf;

    // mask layout detection (lengths >= 256 so mask[0][1] is true):
    const unsigned char* m8 = (const unsigned char*)maskp;
    const int* m32 = (const int*)maskp;
    const bool u8m = (m8[1] != 0);

    // Stage trans^T (swizzled) into both tbuf copies. Coalesced global reads.
#pragma unroll
    for (int p = 0; p < 16; ++p) {
        const int f = p * 256 + tid;        // 0..4095
        const int i = f >> 6, jj = f & 63;  // trans[i][jj]
        const float v = trans[f];
        const int idx = ((((i >> 2) ^ (jj & 7)) << 2) | (i & 3));
        tbuf[0][jj][idx] = v;
        tbuf[1][jj][idx] = v;
    }
    __syncthreads();

    if (w == 0) {
        const int sw = (j & 7);
        const float* emb = em + (size_t)b * TT * KK;
        float score = startT[j] + emb[j];       // t = 0
        const float endv = endT[j];

        float e_cur = emb[KK + j];              // t = 1 prefetch
        int   m_cur = u8m ? (int)m8[b * TT + 1] : m32[b * TT + 1];

        int t = 1;
#pragma clang loop unroll(disable)
        for (; t < TT; ++t) {
            const int tn2 = (t + 1 < TT) ? (t + 1) : (TT - 1);
            const float e_next = emb[(size_t)tn2 * KK + j];     // prefetch next
            const int   m_next = u8m ? (int)m8[b * TT + tn2] : m32[b * TT + tn2];

            if (!m_cur) break;   // length mask: monotone, done forever

            const float* tb = &tbuf[t & 1][j][0];

            float cv[8]; int ci[8];
#pragma unroll
            for (int c = 0; c < 8; ++c) {
                // logical floats i = c*8 .. c*8+7 live in physical blocks (2c)^sw, (2c+1)^sw
                const float4 t0 = *(const float4*)(tb + (((2 * c) ^ sw) << 2));
                const float4 t1 = *(const float4*)(tb + (((2 * c + 1) ^ sw) << 2));
                const float tcv[8] = { t0.x, t0.y, t0.z, t0.w, t1.x, t1.y, t1.z, t1.w };
                float tv[8]; int ti[8];
#pragma unroll
                for (int q = 0; q < 8; ++q) {
                    const int i = c * 8 + q;
                    const float si = __uint_as_float(
                        (unsigned)__builtin_amdgcn_readlane((int)__float_as_uint(score), i));
                    tv[q] = (si + tcv[q]) + e_cur;   // reference association order
                    ti[q] = i;
                }
#pragma unroll
                for (int n = 4; n >= 1; n >>= 1)
#pragma unroll
                    for (int q = 0; q < n; ++q) {
                        const bool cgt = tv[2 * q] >= tv[2 * q + 1];
                        tv[q] = cgt ? tv[2 * q] : tv[2 * q + 1];
                        ti[q] = cgt ? ti[2 * q] : ti[2 * q + 1];
                    }
                cv[c] = tv[0]; ci[c] = ti[0];
            }
#pragma unroll
            for (int n = 4; n >= 1; n >>= 1)
#pragma unroll
                for (int q = 0; q < n; ++q) {
                    const bool cgt = cv[2 * q] >= cv[2 * q + 1];
                    cv[q] = cgt ? cv[2 * q] : cv[2 * q + 1];
                    ci[q] = cgt ? ci[2 * q] : ci[2 * q + 1];
                }
            score = cv[0];
            hist[t][j] = (unsigned char)ci[0];

            e_cur = e_next; m_cur = m_next;
        }
        for (; t < TT; ++t) hist[t][j] = (unsigned char)j;   // identity tail

        score += endv;
        // first-index argmax over 64 lanes (one-time; serial chain is fine)
        float bm = __uint_as_float((unsigned)__builtin_amdgcn_readlane((int)__float_as_uint(score), 0));
        int bt = 0;
#pragma unroll
        for (int i = 1; i < KK; ++i) {
            const float si = __uint_as_float(
                (unsigned)__builtin_amdgcn_readlane((int)__float_as_uint(score), i));
            if (si > bm) { bm = si; bt = i; }
        }
        if (j == 0) bt_sh = bt;
    }

    __syncthreads();   // hist + bt_sh complete; tbuf now dead -> reuse as hypo

    // Phase A: all-hypothesis segment replay; wave w -> segments 2w, 2w+1
#pragma unroll
    for (int ss = 0; ss < 2; ++ss) {
        const int s = w * 2 + ss;
        int tag = j;
        if (s == 7) {
            hypo[7][63][j] = (unsigned char)j;            // tag at t=511
            for (int t = TT - 1; t >= 7 * 64 + 1; --t) {
                tag = hist[t][tag];
                hypo[7][t - 1 - 7 * 64][j] = (unsigned char)tag;
            }
        } else {
            for (int t = (s + 1) * 64; t >= s * 64 + 1; --t) {
                tag = hist[t][tag];
                hypo[s][t - 1 - s * 64][j] = (unsigned char)tag;
            }
        }
    }
    __syncthreads();

    // Phase B: compose boundary tags (uniform; broadcast LDS reads)
    const int bt = bt_sh;
    int rows_[8];
    rows_[7] = bt;
#pragma unroll
    for (int s = 6; s >= 0; --s) rows_[s] = hypo[s + 1][0][rows_[s + 1]];

    // Phase C: emit; wave w -> segments 2w, 2w+1; lane j -> time 64s+j
    float* pb = pred + (size_t)b * TT;
#pragma unroll
    for (int ss = 0; ss < 2; ++ss) {
        const int s = w * 2 + ss;
        pb[s * 64 + j] = (float)hypo[s][j][rows_[s]];
    }
}

extern "C" void kernel_launch(void* const* d_in, const int* in_sizes, int n_in,
                              void* d_out, int out_size, void* d_ws, size_t ws_size,
                              hipStream_t stream) {
    const float* X      = (const float*)d_in[0];
    const void*  mask   = d_in[1];
    const float* W      = (const float*)d_in[2];
    const float* bias   = (const float*)d_in[3];
    const float* startT = (const float*)d_in[4];
    const float* endT   = (const float*)d_in[5];
    const float* trans  = (const float*)d_in[6];

    float* em   = (float*)d_out;
    float* pred = (float*)d_out + (size_t)BB * TT * KK;

    emission_kernel<<<(BB * TT) / BM, 256, 0, stream>>>(X, W, bias, em);
    viterbi_kernel<<<BB, 256, 0, stream>>>(em, mask, startT, endT, trans, pred);
}

// Round 6
// 624.847 us; speedup vs baseline: 4.1214x; 2.0497x over previous
//
#include <hip/hip_runtime.h>
#include <hip/hip_bf16.h>

#define BB 64
#define TT 512
#define FF 1024
#define KK 64

// ---------------- Emission GEMM (round-1 version, measured ~83-88us, 3x) ----------------
#define BM 64
#define BF 64
#define LDA 68  // padded LDS stride: 272 B rows, 16B-aligned, breaks pow-2 bank conflicts

__global__ __launch_bounds__(256)
void emission_kernel(const float* __restrict__ X, const float* __restrict__ W,
                     const float* __restrict__ bias, float* __restrict__ em)
{
    __shared__ float As[BF][LDA];   // As[f][m]  (transposed)
    __shared__ float Bs[BF][LDA];   // Bs[f][k]  (transposed)
    const int tid = threadIdx.x;
    const int row0 = blockIdx.x * BM;
    const int tm = tid & 15;
    const int tn = tid >> 4;
    const int lq = tid & 15;
    const int lr = tid >> 4;

    float acc[4][4];
#pragma unroll
    for (int i = 0; i < 4; ++i)
#pragma unroll
        for (int jj = 0; jj < 4; ++jj) acc[i][jj] = 0.f;

    for (int f0 = 0; f0 < FF; f0 += BF) {
#pragma unroll
        for (int p = 0; p < 4; ++p) {
            const int r = p * 16 + lr;
            float4 a = *(const float4*)(X + (size_t)(row0 + r) * FF + f0 + lq * 4);
            As[lq * 4 + 0][r] = a.x;
            As[lq * 4 + 1][r] = a.y;
            As[lq * 4 + 2][r] = a.z;
            As[lq * 4 + 3][r] = a.w;
            float4 w = *(const float4*)(W + (size_t)r * FF + f0 + lq * 4);
            Bs[lq * 4 + 0][r] = w.x;
            Bs[lq * 4 + 1][r] = w.y;
            Bs[lq * 4 + 2][r] = w.z;
            Bs[lq * 4 + 3][r] = w.w;
        }
        __syncthreads();
#pragma unroll
        for (int f = 0; f < BF; ++f) {
            float4 a = *(const float4*)&As[f][tm * 4];
            float4 b = *(const float4*)&Bs[f][tn * 4];
            acc[0][0] += a.x * b.x; acc[0][1] += a.x * b.y; acc[0][2] += a.x * b.z; acc[0][3] += a.x * b.w;
            acc[1][0] += a.y * b.x; acc[1][1] += a.y * b.y; acc[1][2] += a.y * b.z; acc[1][3] += a.y * b.w;
            acc[2][0] += a.z * b.x; acc[2][1] += a.z * b.y; acc[2][2] += a.z * b.z; acc[2][3] += a.z * b.w;
            acc[3][0] += a.w * b.x; acc[3][1] += a.w * b.y; acc[3][2] += a.w * b.z; acc[3][3] += a.w * b.w;
        }
        __syncthreads();
    }

    const float4 b4 = *(const float4*)(bias + tn * 4);
#pragma unroll
    for (int i = 0; i < 4; ++i) {
        float4 o;
        o.x = acc[i][0] + b4.x;
        o.y = acc[i][1] + b4.y;
        o.z = acc[i][2] + b4.z;
        o.w = acc[i][3] + b4.w;
        *(float4*)(em + (size_t)(row0 + tm * 4 + i) * KK + tn * 4) = o;
    }
}

// ---------------- Viterbi ----------------
// Forward loop = ROUND-1 VERBATIM (serial 64-iter scan, strict >, first-index,
// tc[] local array, one wave, no barriers) + ONE change: distance-1 double-
// buffered prefetch of e/mask so the ~600cy global load latency hides under
// the ~1000cy compute instead of serializing after it.
// Backtrack: 4-wave 8-segment hypothesis replay (validated r2-r5).
__global__ __launch_bounds__(256)
void viterbi_kernel(const float* __restrict__ em, const void* __restrict__ maskp,
                    const float* __restrict__ startT, const float* __restrict__ endT,
                    const float* __restrict__ trans, float* __restrict__ pred)
{
    const int b = blockIdx.x;
    const int tid = threadIdx.x;
    const int w = tid >> 6;
    const int j = tid & 63;

    __shared__ unsigned char hist[TT][KK];     // 32 KB
    __shared__ unsigned char hypo[8][64][64];  // 32 KB
    __shared__ int bt_sh;

    // mask layout detection (lengths >= 256 so mask[0][1] is true):
    const unsigned char* m8 = (const unsigned char*)maskp;
    const int* m32 = (const int*)maskp;
    const bool u8m = (m8[1] != 0);

    if (w == 0) {
        float tc[KK];   // trans column j (as in round 1)
#pragma unroll
        for (int i = 0; i < KK; ++i) tc[i] = trans[i * KK + j];

        const float* emb = em + (size_t)b * TT * KK;
        float score = startT[j] + emb[j];   // t = 0
        const float endv = endT[j];

        float e_cur = emb[KK + j];          // prefetch t = 1
        int   m_cur = u8m ? (int)m8[b * TT + 1] : m32[b * TT + 1];

        int t = 1;
        for (; t < TT; ++t) {
            const int tn2 = (t + 1 < TT) ? (t + 1) : (TT - 1);
            const float e_next = emb[(size_t)tn2 * KK + j];          // prefetch t+1
            const int   m_next = u8m ? (int)m8[b * TT + tn2] : m32[b * TT + tn2];

            if (!m_cur) break;   // length mask: monotone

            // ---- ROUND-1 inner loop, verbatim ----
            float m = -__builtin_inff();
            int idx = 0;
#pragma unroll
            for (int i = 0; i < KK; ++i) {
                const float si = __uint_as_float(
                    __builtin_amdgcn_readlane(__float_as_uint(score), i));
                const float v = (si + tc[i]) + e_cur;   // reference association order
                if (v > m) { m = v; idx = i; }          // strict >: first-index argmax
            }
            score = m;
            hist[t][j] = (unsigned char)idx;
            // --------------------------------------

            e_cur = e_next; m_cur = m_next;
        }
        for (; t < TT; ++t) hist[t][j] = (unsigned char)j;   // identity tail

        score += endv;
        // first-index argmax over 64 lanes (round-1 form)
        float bm = -__builtin_inff();
        int bt = 0;
#pragma unroll
        for (int i = 0; i < KK; ++i) {
            const float si = __uint_as_float(
                __builtin_amdgcn_readlane(__float_as_uint(score), i));
            if (si > bm) { bm = si; bt = i; }
        }
        if (j == 0) bt_sh = bt;
    }

    __syncthreads();   // hist + bt_sh complete; waves 1-3 join here

    // Phase A: all-hypothesis segment replay; wave w -> segments 2w, 2w+1
#pragma unroll
    for (int ss = 0; ss < 2; ++ss) {
        const int s = w * 2 + ss;
        int tag = j;
        if (s == 7) {
            hypo[7][63][j] = (unsigned char)j;            // tag at t=511
            for (int t = TT - 1; t >= 7 * 64 + 1; --t) {
                tag = hist[t][tag];
                hypo[7][t - 1 - 7 * 64][j] = (unsigned char)tag;
            }
        } else {
            for (int t = (s + 1) * 64; t >= s * 64 + 1; --t) {
                tag = hist[t][tag];
                hypo[s][t - 1 - s * 64][j] = (unsigned char)tag;
            }
        }
    }
    __syncthreads();

    // Phase B: compose boundary tags (uniform; broadcast LDS reads)
    const int bt = bt_sh;
    int rows_[8];
    rows_[7] = bt;
#pragma unroll
    for (int s = 6; s >= 0; --s) rows_[s] = hypo[s + 1][0][rows_[s + 1]];

    // Phase C: emit; wave w -> segments 2w, 2w+1; lane j -> time 64s+j
    float* pb = pred + (size_t)b * TT;
#pragma unroll
    for (int ss = 0; ss < 2; ++ss) {
        const int s = w * 2 + ss;
        pb[s * 64 + j] = (float)hypo[s][j][rows_[s]];
    }
}

extern "C" void kernel_launch(void* const* d_in, const int* in_sizes, int n_in,
                              void* d_out, int out_size, void* d_ws, size_t ws_size,
                              hipStream_t stream) {
    const float* X      = (const float*)d_in[0];
    const void*  mask   = d_in[1];
    const float* W      = (const float*)d_in[2];
    const float* bias   = (const float*)d_in[3];
    const float* startT = (const float*)d_in[4];
    const float* endT   = (const float*)d_in[5];
    const float* trans  = (const float*)d_in[6];

    float* em   = (float*)d_out;
    float* pred = (float*)d_out + (size_t)BB * TT * KK;

    emission_kernel<<<(BB * TT) / BM, 256, 0, stream>>>(X, W, bias, em);
    viterbi_kernel<<<BB, 256, 0, stream>>>(em, mask, startT, endT, trans, pred);
}